// Round 1
// baseline (669.221 us; speedup 1.0000x reference)
//
#include <hip/hip_runtime.h>

typedef unsigned short u16;
typedef __bf16 bf16x8 __attribute__((ext_vector_type(8)));
typedef float f32x4v __attribute__((ext_vector_type(4)));
typedef u16 u16x8 __attribute__((ext_vector_type(8)));

__device__ __forceinline__ u16 f2bf(float f) {
  union { float f; unsigned u; } v; v.f = f;
  unsigned r = v.u + 0x7fffu + ((v.u >> 16) & 1u);  // round-to-nearest-even
  return (u16)(r >> 16);
}
__device__ __forceinline__ float bf2f(u16 h) {
  union { unsigned u; float f; } v; v.u = ((unsigned)h) << 16;
  return v.f;
}

#define G2L16(g, l)                                                            \
  __builtin_amdgcn_global_load_lds((__attribute__((address_space(1))) void*)(g), \
                                   (__attribute__((address_space(3))) void*)(l), 16, 0, 0)

// ---------------- transpose + fp32->bf16 convert: in (R x C) -> out (C x R) ----
__global__ __launch_bounds__(256) void k_transpose_bf16(const float* __restrict__ in,
                                                        u16* __restrict__ out, int R, int C) {
  __shared__ float tile[32][33];
  const int c0 = blockIdx.x * 32, r0 = blockIdx.y * 32;
  const int tx = threadIdx.x & 31, ty = threadIdx.x >> 5;
#pragma unroll
  for (int i = 0; i < 4; ++i) {
    int r = ty + i * 8;
    tile[r][tx] = in[(size_t)(r0 + r) * C + c0 + tx];
  }
  __syncthreads();
#pragma unroll
  for (int i = 0; i < 4; ++i) {
    int r = ty + i * 8;  // output row within tile == input col
    out[(size_t)(c0 + r) * R + r0 + tx] = f2bf(tile[tx][r]);
  }
}

// ---------------- PQ table: pq[(e*2+p)][c][n] = sum_k x1[c][k] * We[e][p*1024+k][n]
__global__ __launch_bounds__(256) void k_pq(const float* __restrict__ x1,
                                            const float* __restrict__ We,
                                            float* __restrict__ pq) {
  const int n0 = blockIdx.x * 64;
  const int ep = blockIdx.y;  // e*2+p
  const int e = ep >> 1, p = ep & 1;
  __shared__ float As[64][33];
  __shared__ float Bs[32][68];
  const int t = threadIdx.x;
  const int tx = t & 15, ty = t >> 4;
  float acc[4][4] = {};
  const float* wbase = We + (size_t)e * 2048 * 1024 + (size_t)p * 1024 * 1024;
  for (int k0 = 0; k0 < 1024; k0 += 32) {
#pragma unroll
    for (int i = 0; i < 8; ++i) {
      int idx = t + i * 256;
      As[idx >> 5][idx & 31] = x1[(size_t)(idx >> 5) * 1024 + k0 + (idx & 31)];
    }
#pragma unroll
    for (int i = 0; i < 8; ++i) {
      int idx = t + i * 256;
      Bs[idx >> 6][idx & 63] = wbase[(size_t)(k0 + (idx >> 6)) * 1024 + n0 + (idx & 63)];
    }
    __syncthreads();
#pragma unroll
    for (int kk = 0; kk < 32; ++kk) {
      float av[4];
#pragma unroll
      for (int i = 0; i < 4; ++i) av[i] = As[ty * 4 + i][kk];
      f32x4v bv = *(const f32x4v*)&Bs[kk][tx * 4];
#pragma unroll
      for (int i = 0; i < 4; ++i)
#pragma unroll
        for (int j = 0; j < 4; ++j) acc[i][j] += av[i] * bv[j];
    }
    __syncthreads();
  }
#pragma unroll
  for (int i = 0; i < 4; ++i) {
    float* dst = pq + ((size_t)ep * 64 + ty * 4 + i) * 1024 + n0 + tx * 4;
#pragma unroll
    for (int j = 0; j < 4; ++j) dst[j] = acc[i][j];
  }
}

// ---------------- build Y (8192 x 2048, bf16): [relu(P+Q+be) | x2] ----------
__global__ __launch_bounds__(256) void k_build_y(const float* __restrict__ pq,
                                                 const float* __restrict__ x2,
                                                 const float* __restrict__ be,
                                                 const int* __restrict__ cp,
                                                 const int* __restrict__ vis,
                                                 u16* __restrict__ Y) {
  const int b = blockIdx.x;
  const int t = threadIdx.x;
  const int e = vis[b];
  u16x8 o;
  if (t < 128) {
    const int c0 = cp[2 * b], c1 = cp[2 * b + 1];
    const float* P = pq + ((size_t)(e * 2) * 64 + c0) * 1024 + t * 8;
    const float* Q = pq + ((size_t)(e * 2 + 1) * 64 + c1) * 1024 + t * 8;
    const float* B = be + e * 1024 + t * 8;
#pragma unroll
    for (int i = 0; i < 8; ++i) {
      float v = P[i] + Q[i] + B[i];
      o[i] = f2bf(v > 0.f ? v : 0.f);
    }
    *(u16x8*)(Y + (size_t)b * 2048 + t * 8) = o;
  } else {
    const float* X = x2 + (size_t)b * 1024 + (size_t)(t - 128) * 8;
#pragma unroll
    for (int i = 0; i < 8; ++i) o[i] = f2bf(X[i]);
    *(u16x8*)(Y + (size_t)b * 2048 + 1024 + (size_t)(t - 128) * 8) = o;
  }
}

// ---------------- bf16 MFMA GEMM: C(MxN) = relu(A(MxK) @ BT(NxK)^T + bias) ---
// m97 structure: 128x128 tile, BK=32, global_load_lds width 16, 2-barrier K-loop.
__global__ __launch_bounds__(256) void k_gemm(const u16* __restrict__ A,
                                              const u16* __restrict__ BT,
                                              const float* __restrict__ bias,
                                              u16* __restrict__ C, int M, int N, int K) {
  __shared__ u16 As[128 * 32];
  __shared__ u16 Bs[128 * 32];
  const int tid = threadIdx.x;
  const int lane = tid & 63;
  const int wave = tid >> 6;
  const int tileN = blockIdx.x * 128;
  const int tileM = blockIdx.y * 128;
  const int wm = wave & 1;
  const int wn = wave >> 1;

  f32x4v acc[4][4];
#pragma unroll
  for (int i = 0; i < 4; ++i)
#pragma unroll
    for (int j = 0; j < 4; ++j) acc[i][j] = (f32x4v){0.f, 0.f, 0.f, 0.f};

  const int srow = tid >> 2;        // 0..63
  const int scol = (tid & 3) * 8;   // 0,8,16,24
  const u16* aptr = A + (size_t)(tileM + srow) * K + scol;
  const u16* bptr = BT + (size_t)(tileN + srow) * K + scol;
  u16* asp = As + tid * 8;  // byte offset tid*16; lane0 of wave w at w*1024B
  u16* bsp = Bs + tid * 8;

  const int am = wm * 64 + (lane & 15);
  const int ak = (lane >> 4) * 8;
  const int bn = wn * 64 + (lane & 15);

  for (int k0 = 0; k0 < K; k0 += 32) {
    G2L16(aptr, asp);
    G2L16(aptr + (size_t)64 * K, asp + 2048);
    G2L16(bptr, bsp);
    G2L16(bptr + (size_t)64 * K, bsp + 2048);
    aptr += 32;
    bptr += 32;
    __syncthreads();  // drains vmcnt(0): LDS tiles ready

    bf16x8 af[4], bfr[4];
#pragma unroll
    for (int mi = 0; mi < 4; ++mi)
      af[mi] = *(const bf16x8*)(As + ((am + mi * 16) * 32 + ak));
#pragma unroll
    for (int ni = 0; ni < 4; ++ni)
      bfr[ni] = *(const bf16x8*)(Bs + ((bn + ni * 16) * 32 + ak));
#pragma unroll
    for (int mi = 0; mi < 4; ++mi)
#pragma unroll
      for (int ni = 0; ni < 4; ++ni)
        acc[mi][ni] = __builtin_amdgcn_mfma_f32_16x16x32_bf16(af[mi], bfr[ni], acc[mi][ni], 0, 0, 0);
    __syncthreads();  // all reads done before next stage overwrites
  }

  // C/D layout (m89-verified): col = lane&15, row = (lane>>4)*4 + reg
  const int crow = tileM + wm * 64 + (lane >> 4) * 4;
  const int ccol = tileN + wn * 64 + (lane & 15);
#pragma unroll
  for (int mi = 0; mi < 4; ++mi) {
#pragma unroll
    for (int ni = 0; ni < 4; ++ni) {
      const int c = ccol + ni * 16;
      const float bv = bias[c];
      const int r0 = crow + mi * 16;
#pragma unroll
      for (int r = 0; r < 4; ++r) {
        float v = acc[mi][ni][r] + bv;
        v = v > 0.f ? v : 0.f;
        C[(size_t)(r0 + r) * N + c] = f2bf(v);
      }
    }
  }
}

// ---------------- in-place layernorm over rows of bf16 H (cols = PER*256) ----
template <int PER>
__global__ __launch_bounds__(256) void k_ln(u16* __restrict__ H, const float* __restrict__ g,
                                            const float* __restrict__ bt) {
  const int cols = PER * 256;
  u16* row = H + (size_t)blockIdx.x * cols;
  const int t = threadIdx.x;
  float vals[PER];
  float s = 0.f, ss = 0.f;
#pragma unroll
  for (int j = 0; j < PER; j += 8) {
    u16x8 v = *(const u16x8*)(row + t * PER + j);
#pragma unroll
    for (int i = 0; i < 8; ++i) {
      float f = bf2f(v[i]);
      vals[j + i] = f;
      s += f;
      ss += f * f;
    }
  }
#pragma unroll
  for (int off = 32; off > 0; off >>= 1) {
    s += __shfl_down(s, off, 64);
    ss += __shfl_down(ss, off, 64);
  }
  __shared__ float red[8];
  const int lane = t & 63, wv = t >> 6;
  if (lane == 0) { red[wv] = s; red[4 + wv] = ss; }
  __syncthreads();
  if (t == 0) {
    float S = red[0] + red[1] + red[2] + red[3];
    float SS = red[4] + red[5] + red[6] + red[7];
    float m = S * (1.f / cols);
    float var = SS * (1.f / cols) - m * m;
    red[0] = m;
    red[1] = rsqrtf(var + 1e-5f);
  }
  __syncthreads();
  const float m = red[0], rs = red[1];
#pragma unroll
  for (int j = 0; j < PER; j += 8) {
    u16x8 o;
#pragma unroll
    for (int i = 0; i < 8; ++i) {
      int col = t * PER + j + i;
      o[i] = f2bf((vals[j + i] - m) * rs * g[col] + bt[col]);
    }
    *(u16x8*)(row + t * PER + j) = o;
  }
}

// ---------------- final: out[b] = sigmoid(H2[b,:] . W3 + b3) -----------------
__global__ __launch_bounds__(256) void k_final(const u16* __restrict__ H2,
                                               const float* __restrict__ W3,
                                               const float* __restrict__ b3,
                                               float* __restrict__ out) {
  const int b = blockIdx.x, t = threadIdx.x;
  const u16* row = H2 + (size_t)b * 2048;
  u16x8 v = *(const u16x8*)(row + t * 8);
  float s = 0.f;
#pragma unroll
  for (int i = 0; i < 8; ++i) s += bf2f(v[i]) * W3[t * 8 + i];
#pragma unroll
  for (int off = 32; off > 0; off >>= 1) s += __shfl_down(s, off, 64);
  __shared__ float red[4];
  if ((t & 63) == 0) red[t >> 6] = s;
  __syncthreads();
  if (t == 0) {
    float S = red[0] + red[1] + red[2] + red[3] + b3[0];
    out[b] = 1.f / (1.f + expf(-S));
  }
}

extern "C" void kernel_launch(void* const* d_in, const int* in_sizes, int n_in,
                              void* d_out, int out_size, void* d_ws, size_t ws_size,
                              hipStream_t stream) {
  const float* x1 = (const float*)d_in[0];    // (1,64,1024)
  const float* x2 = (const float*)d_in[1];    // (8192,1024)
  const float* We = (const float*)d_in[2];    // (4,2048,1024)
  const float* be = (const float*)d_in[3];    // (4,1024)
  const float* W1 = (const float*)d_in[4];    // (2048,4096)
  const float* b1 = (const float*)d_in[5];
  const float* g1 = (const float*)d_in[6];
  const float* bt1 = (const float*)d_in[7];
  const float* W2 = (const float*)d_in[8];    // (4096,2048)
  const float* b2 = (const float*)d_in[9];
  const float* g2 = (const float*)d_in[10];
  const float* bt2 = (const float*)d_in[11];
  const float* W3 = (const float*)d_in[12];   // (2048,1)
  const float* b3 = (const float*)d_in[13];
  const int* cp = (const int*)d_in[14];       // (8192,2)
  const int* vis = (const int*)d_in[15];      // (8192,)
  float* out = (float*)d_out;

  char* ws = (char*)d_ws;
  u16* W1T = (u16*)(ws);                  // 4096x2048 bf16 = 16 MiB
  u16* W2T = (u16*)(ws + 16777216);       // 2048x4096 bf16 = 16 MiB
  u16* Y   = (u16*)(ws + 33554432);       // 8192x2048 bf16 = 32 MiB (reused as H2)
  u16* H1  = (u16*)(ws + 67108864);       // 8192x4096 bf16 = 64 MiB
  float* PQ = (float*)(ws + 134217728);   // 8x64x1024 fp32 = 2 MiB
  u16* H2 = Y;

  k_transpose_bf16<<<dim3(4096 / 32, 2048 / 32), 256, 0, stream>>>(W1, W1T, 2048, 4096);
  k_transpose_bf16<<<dim3(2048 / 32, 4096 / 32), 256, 0, stream>>>(W2, W2T, 4096, 2048);
  k_pq<<<dim3(16, 8), 256, 0, stream>>>(x1, We, PQ);
  k_build_y<<<8192, 256, 0, stream>>>(PQ, x2, be, cp, vis, Y);
  k_gemm<<<dim3(4096 / 128, 8192 / 128), 256, 0, stream>>>(Y, W1T, b1, H1, 8192, 4096, 2048);
  k_ln<16><<<8192, 256, 0, stream>>>(H1, g1, bt1);
  k_gemm<<<dim3(2048 / 128, 8192 / 128), 256, 0, stream>>>(H1, W2T, b2, H2, 8192, 2048, 4096);
  k_ln<8><<<8192, 256, 0, stream>>>(H2, g2, bt2);
  k_final<<<8192, 256, 0, stream>>>(H2, W3, b3, out);
}